// Round 1
// baseline (496.624 us; speedup 1.0000x reference)
//
#include <hip/hip_runtime.h>
#include <math.h>

#define T_DIM 4096
#define D_DIM 1024
#define NUM_PAT 8
#define PAT_LEN 128
#define HALF_PAT 64

struct BatchParams {
    float mean;
    float inv;
    int lo[NUM_PAT];
    int hi[NUM_PAT];
    int pad[14];   // pad to 128 B
};

// ---------------------------------------------------------------------------
// Kernel 1: per-row sum and sum-of-squares in fp64. One wave (64 lanes) per
// row of D=1024 floats; 4 waves per 256-thread block. Memory-bound (reads x).
// ---------------------------------------------------------------------------
__global__ __launch_bounds__(256) void row_reduce_kernel(
        const float* __restrict__ x,
        double* __restrict__ rowsum,
        double* __restrict__ rowsumsq,
        int nrows) {
    int wave = (int)((blockIdx.x * blockDim.x + threadIdx.x) >> 6);
    int lane = threadIdx.x & 63;
    if (wave >= nrows) return;
    const float4* xp = (const float4*)(x + (size_t)wave * D_DIM);
    double s1 = 0.0, s2 = 0.0;
#pragma unroll
    for (int q = 0; q < 4; ++q) {
        float4 v = xp[lane + q * 64];
        double a = (double)v.x, b = (double)v.y, c = (double)v.z, d = (double)v.w;
        s1 += (a + b) + (c + d);
        s2 += (a * a + b * b) + (c * c + d * d);
    }
#pragma unroll
    for (int off = 32; off >= 1; off >>= 1) {
        s1 += __shfl_down(s1, off, 64);
        s2 += __shfl_down(s2, off, 64);
    }
    if (lane == 0) {
        rowsum[wave] = s1;
        rowsumsq[wave] = s2;
    }
}

// ---------------------------------------------------------------------------
// Kernel 2: one 256-thread block per batch.
//  - xt (fp32) from rowsum; peak mask (local max over 3-window, -inf borders)
//  - iterative top-8 argmax with jax.lax.top_k tie-break (smaller index wins)
//  - window-gathered mean / unbiased std via rowsum/rowsumsq (fp64)
// ---------------------------------------------------------------------------
__global__ __launch_bounds__(256) void select_kernel(
        const double* __restrict__ rowsum,
        const double* __restrict__ rowsumsq,
        BatchParams* __restrict__ params) {
    int b = blockIdx.x;
    int j = threadIdx.x;
    __shared__ float xs[T_DIM];
    __shared__ float pv[T_DIM];
    __shared__ float redv[256];
    __shared__ int   redi[256];
    __shared__ int   ind[NUM_PAT];
    __shared__ double dv1[256], dv2[256];

    const double* rs = rowsum   + (size_t)b * T_DIM;
    const double* rq = rowsumsq + (size_t)b * T_DIM;

    for (int t = j; t < T_DIM; t += 256) xs[t] = (float)rs[t];
    __syncthreads();

    for (int t = j; t < T_DIM; t += 256) {
        float c = xs[t];
        float l = (t > 0)         ? xs[t - 1] : -INFINITY;
        float r = (t < T_DIM - 1) ? xs[t + 1] : -INFINITY;
        pv[t] = (c >= l && c >= r) ? c : 0.0f;
    }
    __syncthreads();

    for (int k = 0; k < NUM_PAT; ++k) {
        float bv = -INFINITY;
        int   bi = 0x7fffffff;
        int t0 = j * 16;
#pragma unroll
        for (int q = 0; q < 16; ++q) {
            float v = pv[t0 + q];
            if (v > bv) { bv = v; bi = t0 + q; }   // strict > keeps lowest index
        }
        redv[j] = bv; redi[j] = bi;
        __syncthreads();
        for (int s = 128; s >= 1; s >>= 1) {
            if (j < s) {
                float ov = redv[j + s]; int oi = redi[j + s];
                if (ov > redv[j] || (ov == redv[j] && oi < redi[j])) {
                    redv[j] = ov; redi[j] = oi;
                }
            }
            __syncthreads();
        }
        if (j == 0) {
            ind[k] = redi[0];
            pv[redi[0]] = -INFINITY;   // remove from next selection round
        }
        __syncthreads();
    }

    // Gather-window sums over the M = 8*128 (possibly duplicated) row indices.
    double s1 = 0.0, s2 = 0.0;
    for (int m = j; m < NUM_PAT * PAT_LEN; m += 256) {
        int k = m >> 7;
        int t = ind[k] + (m & (PAT_LEN - 1)) - HALF_PAT;
        t = min(max(t, 0), T_DIM - 1);
        s1 += rs[t];
        s2 += rq[t];
    }
    dv1[j] = s1; dv2[j] = s2;
    __syncthreads();
    for (int s = 128; s >= 1; s >>= 1) {
        if (j < s) { dv1[j] += dv1[j + s]; dv2[j] += dv2[j + s]; }
        __syncthreads();
    }
    if (j == 0) {
        double S1 = dv1[0], S2 = dv2[0];
        const double N = (double)(NUM_PAT * PAT_LEN) * (double)D_DIM;
        double mean = S1 / N;
        double var  = (S2 - S1 * S1 / N) / (N - 1.0);
        if (var < 0.0) var = 0.0;
        float stdf = (float)sqrt(var);
        params[b].mean = (float)mean;
        params[b].inv  = 1.0f / (stdf + 1e-8f);
#pragma unroll
        for (int k = 0; k < NUM_PAT; ++k) {
            params[b].lo[k] = max(0, ind[k] - HALF_PAT);
            params[b].hi[k] = min(T_DIM - 1, ind[k] + HALF_PAT - 1);
        }
    }
}

// ---------------------------------------------------------------------------
// Kernel 3: elementwise apply. One 256-thread block per (b,t) row (256 x
// float4 = 1024 floats). Mask is uniform per block: 8 interval tests against
// the clipped windows; scatter-set 2.0 -> sigmoid 0.880797, else -3.0 ->
// sigmoid 0.0474259.
// ---------------------------------------------------------------------------
__global__ __launch_bounds__(256) void apply_kernel(
        const float* __restrict__ x,
        const float* __restrict__ gamma,
        const float* __restrict__ beta,
        const BatchParams* __restrict__ params,
        float* __restrict__ out) {
    int blk = blockIdx.x;          // b*T + t
    int b = blk >> 12;             // T = 4096
    int t = blk & (T_DIM - 1);
    const BatchParams* P = params + b;
    bool covered = false;
#pragma unroll
    for (int k = 0; k < NUM_PAT; ++k)
        covered |= (t >= P->lo[k] && t <= P->hi[k]);
    float mask = covered ? (float)0.8807970779778823 : (float)0.04742587317756678;
    float mean = P->mean;
    float inv  = P->inv;

    size_t base = (size_t)blk * D_DIM;
    int d4 = threadIdx.x;
    float4 xv = ((const float4*)(x + base))[d4];
    float4 g  = ((const float4*)gamma)[d4];
    float4 bt = ((const float4*)beta)[d4];
    float4 o;
    o.x = (g.x * ((xv.x - mean) * inv) + bt.x) * mask;
    o.y = (g.y * ((xv.y - mean) * inv) + bt.y) * mask;
    o.z = (g.z * ((xv.z - mean) * inv) + bt.z) * mask;
    o.w = (g.w * ((xv.w - mean) * inv) + bt.w) * mask;
    ((float4*)(out + base))[d4] = o;
}

// ---------------------------------------------------------------------------
extern "C" void kernel_launch(void* const* d_in, const int* in_sizes, int n_in,
                              void* d_out, int out_size, void* d_ws, size_t ws_size,
                              hipStream_t stream) {
    const float* x     = (const float*)d_in[0];
    const float* gamma = (const float*)d_in[1];
    const float* beta  = (const float*)d_in[2];
    float* out = (float*)d_out;

    int total = in_sizes[0];
    int B = total / (T_DIM * D_DIM);
    int nrows = B * T_DIM;

    double* rowsum   = (double*)d_ws;
    double* rowsumsq = rowsum + nrows;
    BatchParams* params =
        (BatchParams*)((char*)d_ws + 2 * (size_t)nrows * sizeof(double));

    row_reduce_kernel<<<(nrows + 3) / 4, 256, 0, stream>>>(x, rowsum, rowsumsq, nrows);
    select_kernel<<<B, 256, 0, stream>>>(rowsum, rowsumsq, params);
    apply_kernel<<<nrows, 256, 0, stream>>>(x, gamma, beta, params, out);
}

// Round 2
// 487.842 us; speedup vs baseline: 1.0180x; 1.0180x over previous
//
#include <hip/hip_runtime.h>
#include <math.h>

#define T_DIM 4096
#define D_DIM 1024
#define NUM_PAT 8
#define PAT_LEN 128
#define HALF_PAT 64

typedef __attribute__((ext_vector_type(4))) float f4;

struct BatchParams {
    float mean;
    float inv;
    int lo[NUM_PAT];
    int hi[NUM_PAT];
    int pad[14];   // pad to 128 B
};

// ---------------------------------------------------------------------------
// Kernel 1: per-row sum and sum-of-squares in fp64. One wave (64 lanes) per
// row of D=1024 floats; 4 waves per 256-thread block. Memory-bound (reads x,
// 256 MB). Normal (caching) loads on purpose: pulls x into L3 for kernel 3.
// ---------------------------------------------------------------------------
__global__ __launch_bounds__(256) void row_reduce_kernel(
        const float* __restrict__ x,
        double* __restrict__ rowsum,
        double* __restrict__ rowsumsq,
        int nrows) {
    int wave = (int)((blockIdx.x * blockDim.x + threadIdx.x) >> 6);
    int lane = threadIdx.x & 63;
    if (wave >= nrows) return;
    const float4* xp = (const float4*)(x + (size_t)wave * D_DIM);
    float4 v[4];
#pragma unroll
    for (int q = 0; q < 4; ++q) v[q] = xp[lane + q * 64];   // 4 indep loads in flight
    double s1 = 0.0, s2 = 0.0;
#pragma unroll
    for (int q = 0; q < 4; ++q) {
        double a = (double)v[q].x, b = (double)v[q].y;
        double c = (double)v[q].z, d = (double)v[q].w;
        s1 += (a + b) + (c + d);
        s2 += (a * a + b * b) + (c * c + d * d);
    }
#pragma unroll
    for (int off = 32; off >= 1; off >>= 1) {
        s1 += __shfl_down(s1, off, 64);
        s2 += __shfl_down(s2, off, 64);
    }
    if (lane == 0) {
        rowsum[wave] = s1;
        rowsumsq[wave] = s2;
    }
}

// ---------------------------------------------------------------------------
// Kernel 2: one 256-thread block per batch.
//  - xt (fp32) from rowsum; peak mask (local max over 3-window, -inf borders)
//  - iterative top-8 argmax with jax.lax.top_k tie-break (smaller index wins)
//  - window-gathered mean / unbiased std via rowsum/rowsumsq (fp64)
// Scan uses stride-256 access: bank = j%32, conflict-free (j*16 scan was
// 32-way conflicted on banks {0,16}).
// ---------------------------------------------------------------------------
__global__ __launch_bounds__(256) void select_kernel(
        const double* __restrict__ rowsum,
        const double* __restrict__ rowsumsq,
        BatchParams* __restrict__ params) {
    int b = blockIdx.x;
    int j = threadIdx.x;
    __shared__ float xs[T_DIM];
    __shared__ float pv[T_DIM];
    __shared__ float redv[256];
    __shared__ int   redi[256];
    __shared__ int   ind[NUM_PAT];
    __shared__ double dv1[256], dv2[256];

    const double* rs = rowsum   + (size_t)b * T_DIM;
    const double* rq = rowsumsq + (size_t)b * T_DIM;

    for (int t = j; t < T_DIM; t += 256) xs[t] = (float)rs[t];
    __syncthreads();

    for (int t = j; t < T_DIM; t += 256) {
        float c = xs[t];
        float l = (t > 0)         ? xs[t - 1] : -INFINITY;
        float r = (t < T_DIM - 1) ? xs[t + 1] : -INFINITY;
        pv[t] = (c >= l && c >= r) ? c : 0.0f;
    }
    __syncthreads();

    for (int k = 0; k < NUM_PAT; ++k) {
        float bv = -INFINITY;
        int   bi = 0x7fffffff;
#pragma unroll
        for (int q = 0; q < 16; ++q) {
            int t = j + q * 256;              // ascending t per thread
            float v = pv[t];
            if (v > bv) { bv = v; bi = t; }   // strict > keeps lowest index
        }
        redv[j] = bv; redi[j] = bi;
        __syncthreads();
        for (int s = 128; s >= 1; s >>= 1) {
            if (j < s) {
                float ov = redv[j + s]; int oi = redi[j + s];
                if (ov > redv[j] || (ov == redv[j] && oi < redi[j])) {
                    redv[j] = ov; redi[j] = oi;
                }
            }
            __syncthreads();
        }
        if (j == 0) {
            ind[k] = redi[0];
            pv[redi[0]] = -INFINITY;   // remove from next selection round
        }
        __syncthreads();
    }

    // Gather-window sums over the M = 8*128 (possibly duplicated) row indices.
    double s1 = 0.0, s2 = 0.0;
    for (int m = j; m < NUM_PAT * PAT_LEN; m += 256) {
        int k = m >> 7;
        int t = ind[k] + (m & (PAT_LEN - 1)) - HALF_PAT;
        t = min(max(t, 0), T_DIM - 1);
        s1 += rs[t];
        s2 += rq[t];
    }
    dv1[j] = s1; dv2[j] = s2;
    __syncthreads();
    for (int s = 128; s >= 1; s >>= 1) {
        if (j < s) { dv1[j] += dv1[j + s]; dv2[j] += dv2[j + s]; }
        __syncthreads();
    }
    if (j == 0) {
        double S1 = dv1[0], S2 = dv2[0];
        const double N = (double)(NUM_PAT * PAT_LEN) * (double)D_DIM;
        double mean = S1 / N;
        double var  = (S2 - S1 * S1 / N) / (N - 1.0);
        if (var < 0.0) var = 0.0;
        float stdf = (float)sqrt(var);
        params[b].mean = (float)mean;
        params[b].inv  = 1.0f / (stdf + 1e-8f);
#pragma unroll
        for (int k = 0; k < NUM_PAT; ++k) {
            params[b].lo[k] = max(0, ind[k] - HALF_PAT);
            params[b].hi[k] = min(T_DIM - 1, ind[k] + HALF_PAT - 1);
        }
    }
}

// ---------------------------------------------------------------------------
// Kernel 3: elementwise apply. 4 rows per 256-thread block, one wave per row
// (mask & params wave-uniform -> zero divergence). Non-temporal stores keep
// `out` from evicting x in L2/L3 (x has no reuse after this, out is never
// re-read).
// ---------------------------------------------------------------------------
__global__ __launch_bounds__(256) void apply_kernel(
        const float* __restrict__ x,
        const float* __restrict__ gamma,
        const float* __restrict__ beta,
        const BatchParams* __restrict__ params,
        float* __restrict__ out) {
    int row  = (blockIdx.x << 2) + (threadIdx.x >> 6);  // 4 rows/block
    int lane = threadIdx.x & 63;
    int b = row >> 12;                                  // T = 4096 rows/batch
    int t = row & (T_DIM - 1);
    const BatchParams* P = params + b;
    bool covered = false;
#pragma unroll
    for (int k = 0; k < NUM_PAT; ++k)
        covered |= (t >= P->lo[k] && t <= P->hi[k]);
    float mask = covered ? (float)0.8807970779778823 : (float)0.04742587317756678;
    float mean = P->mean;
    float inv  = P->inv;

    size_t base = (size_t)row * D_DIM;
    const float4* xp = (const float4*)(x + base);
    float4*       op = (float4*)(out + base);
    const float4* gp = (const float4*)gamma;
    const float4* bp = (const float4*)beta;

    float4 xv[4], g[4], bt[4];
#pragma unroll
    for (int q = 0; q < 4; ++q) {
        int c4 = lane + q * 64;
        xv[q] = xp[c4];
        g[q]  = gp[c4];
        bt[q] = bp[c4];
    }
#pragma unroll
    for (int q = 0; q < 4; ++q) {
        f4 o;
        o.x = (g[q].x * ((xv[q].x - mean) * inv) + bt[q].x) * mask;
        o.y = (g[q].y * ((xv[q].y - mean) * inv) + bt[q].y) * mask;
        o.z = (g[q].z * ((xv[q].z - mean) * inv) + bt[q].z) * mask;
        o.w = (g[q].w * ((xv[q].w - mean) * inv) + bt[q].w) * mask;
        __builtin_nontemporal_store(o, (f4*)(op + lane + q * 64));
    }
}

// ---------------------------------------------------------------------------
extern "C" void kernel_launch(void* const* d_in, const int* in_sizes, int n_in,
                              void* d_out, int out_size, void* d_ws, size_t ws_size,
                              hipStream_t stream) {
    const float* x     = (const float*)d_in[0];
    const float* gamma = (const float*)d_in[1];
    const float* beta  = (const float*)d_in[2];
    float* out = (float*)d_out;

    int total = in_sizes[0];
    int B = total / (T_DIM * D_DIM);
    int nrows = B * T_DIM;

    double* rowsum   = (double*)d_ws;
    double* rowsumsq = rowsum + nrows;
    BatchParams* params =
        (BatchParams*)((char*)d_ws + 2 * (size_t)nrows * sizeof(double));

    row_reduce_kernel<<<(nrows + 3) / 4, 256, 0, stream>>>(x, rowsum, rowsumsq, nrows);
    select_kernel<<<B, 256, 0, stream>>>(rowsum, rowsumsq, params);
    apply_kernel<<<nrows / 4, 256, 0, stream>>>(x, gamma, beta, params, out);
}